// Round 1
// baseline (4014.738 us; speedup 1.0000x reference)
//
#include <hip/hip_runtime.h>
#include <cstdint>

#define DEV __device__ __forceinline__

typedef short bfrag __attribute__((ext_vector_type(8)));   // 8 bf16 (4 VGPRs)
typedef float ffrag __attribute__((ext_vector_type(4)));   // 4 f32 acc

// ---------- constants ----------
constexpr int SE = 400, SD = 50, BB = 32;
constexpr int HH = 512, INW = 512, AA = 128;
constexpr int VF = 1024, VV = 32000;

// ---------- helpers ----------
DEV ushort f2bf(float f) {
    uint32_t u = __float_as_uint(f);
    u = (u + 0x7FFF + ((u >> 16) & 1)) >> 16;   // RNE
    return (ushort)u;
}
DEV float sigm_(float x) { return 1.f / (1.f + __expf(-x)); }
DEV float tanh_(float x) { float e = __expf(2.f * x); return 1.f - 2.f / (e + 1.f); }

DEV void gload_lds16(const void* g, void* l) {
    __builtin_amdgcn_global_load_lds((const __attribute__((address_space(1))) uint32_t*)g,
                                     (__attribute__((address_space(3))) uint32_t*)l, 16, 0, 0);
}

// ---------- f32 -> bf16 converters ----------
__global__ __launch_bounds__(256) void k_cvt_flat(const float* __restrict__ s,
                                                  ushort* __restrict__ d, long n4) {
    long i = (long)blockIdx.x * 256 + threadIdx.x;
    if (i >= n4) return;
    float4 v = ((const float4*)s)[i];
    ushort4 o;
    o.x = f2bf(v.x); o.y = f2bf(v.y); o.z = f2bf(v.z); o.w = f2bf(v.w);
    ((ushort4*)d)[i] = o;
}

__global__ __launch_bounds__(256) void k_cvt_strided(const float* __restrict__ s,
                                                     ushort* __restrict__ d,
                                                     int rows, int cols, int stride, int coff) {
    int i = blockIdx.x * 256 + threadIdx.x;
    if (i >= rows * cols) return;
    int r = i / cols, c = i - r * cols;
    d[i] = f2bf(s[(size_t)r * stride + coff + c]);
}

// ---------- fold encoder state + reduce_dim ----------
// grid: (2 jchunk, 32 b, 4 z) z: bit0 = layer, bit1 = is_cell
__global__ __launch_bounds__(256) void k_fold(const float* __restrict__ hid,
                                              const float* __restrict__ cel,
                                              const float* __restrict__ W_red,
                                              const float* __restrict__ b_red,
                                              float* __restrict__ h0, float* __restrict__ h1,
                                              float* __restrict__ c0, float* __restrict__ c1) {
    int tid = threadIdx.x;
    int j = blockIdx.x * 256 + tid;
    int b = blockIdx.y;
    int l = blockIdx.z & 1;
    bool is_c = blockIdx.z >> 1;
    const float* src = is_c ? cel : hid;
    __shared__ float xs[1024];
    for (int i = tid; i < 512; i += 256) {
        xs[i]       = src[((size_t)l * BB + b) * HH + i];
        xs[512 + i] = src[((size_t)(l + 2) * BB + b) * HH + i];
    }
    __syncthreads();
    const float4* w  = (const float4*)(W_red + (size_t)j * 1024);
    const float4* xv = (const float4*)xs;
    float acc = b_red[j];
    for (int k = 0; k < 256; k++) {
        float4 a = w[k], x = xv[k];
        acc += a.x * x.x + a.y * x.y + a.z * x.z + a.w * x.w;
    }
    float* dst = is_c ? (l ? c1 : c0) : (l ? h1 : h0);
    dst[(size_t)b * HH + j] = acc;
}

// ---------- LSTM cell ----------
// grid: (8 jchunk, 32 b), 256 threads = 4 waves, wave q computes gate q for 64 j
__global__ __launch_bounds__(256) void k_lstm(const float* __restrict__ x,
                                              const float* __restrict__ h_in,
                                              const float* __restrict__ W_ih,
                                              const float* __restrict__ W_hh,
                                              const float* __restrict__ b_ih,
                                              const float* __restrict__ b_hh,
                                              float* __restrict__ c,
                                              float* __restrict__ h_out,
                                              float* __restrict__ out_opt) {
    int tid = threadIdx.x;
    int b = blockIdx.y;
    int jbase = blockIdx.x * 64;
    int q = tid >> 6, l = tid & 63;
    int j = jbase + l;
    __shared__ float xs[512], hs[512];
    __shared__ float g_lds[4][64];
    for (int i = tid; i < 512; i += 256) {
        xs[i] = x[(size_t)b * 512 + i];
        hs[i] = h_in[(size_t)b * 512 + i];
    }
    __syncthreads();
    int row = q * 512 + j;
    const float4* wi = (const float4*)(W_ih + (size_t)row * 512);
    const float4* wh = (const float4*)(W_hh + (size_t)row * 512);
    const float4* xv = (const float4*)xs;
    const float4* hv = (const float4*)hs;
    float acc = b_ih[row] + b_hh[row];
    #pragma unroll 4
    for (int k = 0; k < 128; k++) {
        float4 a = wi[k], xx = xv[k];
        acc += a.x * xx.x + a.y * xx.y + a.z * xx.z + a.w * xx.w;
        float4 bq = wh[k], hh = hv[k];
        acc += bq.x * hh.x + bq.y * hh.y + bq.z * hh.z + bq.w * hh.w;
    }
    g_lds[q][l] = acc;
    __syncthreads();
    if (tid < 64) {
        int jj = jbase + tid;
        float ig = sigm_(g_lds[0][tid]);
        float fg = sigm_(g_lds[1][tid]);
        float gg = tanh_(g_lds[2][tid]);
        float og = sigm_(g_lds[3][tid]);
        size_t idx = (size_t)b * 512 + jj;
        float cn = fg * c[idx] + ig * gg;
        c[idx] = cn;
        float hn = og * tanh_(cn);
        h_out[idx] = hn;
        if (out_opt) out_opt[idx] = hn;
    }
}

// ---------- write final hidden/cell states ----------
__global__ __launch_bounds__(256) void k_states(const float* __restrict__ h0,
                                                const float* __restrict__ h1,
                                                const float* __restrict__ c0,
                                                const float* __restrict__ c1,
                                                float* __restrict__ out) {
    int i = blockIdx.x * 256 + threadIdx.x;
    if (i >= BB * HH) return;
    out[i]                 = h0[i];
    out[BB * HH + i]       = h1[i];
    out[2 * BB * HH + i]   = c0[i];
    out[3 * BB * HH + i]   = c1[i];
}

// ---------- bf16 MFMA GEMM: C[M,N] = X[M,K] @ W[N,K]^T + bias ----------
// BM=64 BN=128 BK=32, 4 waves, wave (wm,wn) owns 32x64, 2x4 frags of 16x16
template <bool OUT_BF16>
__global__ __launch_bounds__(256) void k_gemm(const ushort* __restrict__ X,
                                              const ushort* __restrict__ W,
                                              float* __restrict__ Cf,
                                              ushort* __restrict__ Cb,
                                              const float* __restrict__ bias,
                                              int M, int N, int K) {
    __shared__ ushort As[64 * 32];
    __shared__ ushort Bs[128 * 32];
    const int tid = threadIdx.x;
    const int wave = tid >> 6, lane = tid & 63;
    const int m0 = blockIdx.x * 64, n0 = blockIdx.y * 128;
    const int lr = lane & 15, lk = lane >> 4;
    const int wm = wave >> 1, wn = wave & 1;

    ffrag acc[2][4];
    #pragma unroll
    for (int i = 0; i < 2; i++)
        #pragma unroll
        for (int j = 0; j < 4; j++) acc[i][j] = (ffrag){0.f, 0.f, 0.f, 0.f};

    const int sr = tid >> 2;        // 0..63
    const int sc = (tid & 3) * 8;   // 0,8,16,24
    const ushort* Ag  = X + (size_t)(m0 + sr) * K + sc;
    const ushort* Bg0 = W + (size_t)(n0 + sr) * K + sc;
    const ushort* Bg1 = W + (size_t)(n0 + 64 + sr) * K + sc;
    // wave-uniform LDS bases: lane writes base + lane*16B (linear layout)
    ushort* As_w  = As + wave * 512;
    ushort* Bs_w0 = Bs + wave * 512;
    ushort* Bs_w1 = Bs + 2048 + wave * 512;

    for (int k0 = 0; k0 < K; k0 += 32) {
        gload_lds16(Ag + k0, As_w);
        gload_lds16(Bg0 + k0, Bs_w0);
        gload_lds16(Bg1 + k0, Bs_w1);
        __syncthreads();   // drains vmcnt (global_load_lds) + barrier
        bfrag a[2], bfr[4];
        #pragma unroll
        for (int mf = 0; mf < 2; mf++) {
            int row = wm * 32 + mf * 16 + lr;
            a[mf] = *(const bfrag*)&As[row * 32 + lk * 8];
        }
        #pragma unroll
        for (int nf = 0; nf < 4; nf++) {
            int col = wn * 64 + nf * 16 + lr;
            bfr[nf] = *(const bfrag*)&Bs[col * 32 + lk * 8];
        }
        #pragma unroll
        for (int mf = 0; mf < 2; mf++)
            #pragma unroll
            for (int nf = 0; nf < 4; nf++)
                acc[mf][nf] = __builtin_amdgcn_mfma_f32_16x16x32_bf16(a[mf], bfr[nf], acc[mf][nf], 0, 0, 0);
        __syncthreads();
    }

    #pragma unroll
    for (int mf = 0; mf < 2; mf++) {
        int rbase = m0 + wm * 32 + mf * 16 + lk * 4;
        #pragma unroll
        for (int nf = 0; nf < 4; nf++) {
            int cc = n0 + wn * 64 + nf * 16 + lr;
            float bv = bias ? bias[cc] : 0.f;
            #pragma unroll
            for (int r = 0; r < 4; r++) {
                float v = acc[mf][nf][r] + bv;
                if (OUT_BF16) Cb[(size_t)(rbase + r) * N + cc] = f2bf(v);
                else          Cf[(size_t)(rbase + r) * N + cc] = v;
            }
        }
    }
}

// ---------- attention scores + softmax over encoder axis ----------
// grid: (50 t, 32 b), 256 threads
__global__ __launch_bounds__(256) void k_scores(const float* __restrict__ encp,  // [400][32][128]
                                                const float* __restrict__ decp,  // [50][32][128]
                                                const float* __restrict__ v_att, // [128]
                                                float* __restrict__ attn) {      // [32][50][400]
    int t = blockIdx.x, b = blockIdx.y, tid = threadIdx.x;
    __shared__ float dp[128], vv[128];
    __shared__ float e_lds[400];
    __shared__ float red[8];
    if (tid < 128) {
        dp[tid] = decp[((size_t)t * BB + b) * AA + tid];
        vv[tid] = v_att[tid];
    }
    __syncthreads();
    for (int s = tid; s < SE; s += 256) {
        const float* ep = encp + ((size_t)s * BB + b) * AA;
        float a0 = 0.f;
        #pragma unroll 4
        for (int a = 0; a < AA; a++) a0 += vv[a] * tanh_(ep[a] + dp[a]);
        e_lds[s] = a0;
    }
    __syncthreads();
    float m = -1e30f;
    for (int s = tid; s < SE; s += 256) m = fmaxf(m, e_lds[s]);
    #pragma unroll
    for (int o = 32; o > 0; o >>= 1) m = fmaxf(m, __shfl_xor(m, o));
    if ((tid & 63) == 0) red[tid >> 6] = m;
    __syncthreads();
    m = fmaxf(fmaxf(red[0], red[1]), fmaxf(red[2], red[3]));
    float sum = 0.f;
    for (int s = tid; s < SE; s += 256) {
        float ex = __expf(e_lds[s] - m);
        e_lds[s] = ex;
        sum += ex;
    }
    #pragma unroll
    for (int o = 32; o > 0; o >>= 1) sum += __shfl_xor(sum, o);
    if ((tid & 63) == 0) red[4 + (tid >> 6)] = sum;
    __syncthreads();
    float inv = 1.f / (red[4] + red[5] + red[6] + red[7]);
    for (int s = tid; s < SE; s += 256)
        attn[((size_t)b * SD + t) * SE + s] = e_lds[s] * inv;
}

// ---------- context = attn^T @ output_enc ----------
// grid: (32 b, 4 nchunk, 2 thalf), 256 threads; attn chunk [25][400] in LDS
__global__ __launch_bounds__(256) void k_context(const float* __restrict__ attn, // [32][50][400]
                                                 const float* __restrict__ oe,   // [400][32][1024]
                                                 float* __restrict__ ctx) {      // [50][32][1024]
    int b = blockIdx.x, nc = blockIdx.y, th = blockIdx.z, tid = threadIdx.x;
    __shared__ float at[25][400];
    const float* ap = attn + ((size_t)b * SD + th * 25) * SE;
    for (int i = tid; i < 25 * 400; i += 256) at[i / 400][i % 400] = ap[i];
    __syncthreads();
    int n = nc * 256 + tid;
    float acc[25];
    #pragma unroll
    for (int i = 0; i < 25; i++) acc[i] = 0.f;
    for (int s = 0; s < SE; s++) {
        float v = oe[((size_t)s * BB + b) * 1024 + n];
        #pragma unroll
        for (int tt = 0; tt < 25; tt++) acc[tt] += at[tt][s] * v;
    }
    #pragma unroll
    for (int tt = 0; tt < 25; tt++)
        ctx[(((size_t)(th * 25 + tt)) * BB + b) * 1024 + n] = acc[tt];
}

// ---------- concat [output_dec, context] -> bf16 X1 [1600][1536] ----------
__global__ __launch_bounds__(256) void k_concat(const float* __restrict__ od,   // [1600][512]
                                                const float* __restrict__ ctx,  // [1600][1024]
                                                ushort* __restrict__ x1) {
    int i = blockIdx.x * 256 + threadIdx.x;
    if (i >= 1600 * 1536) return;
    int r = i / 1536, c = i - r * 1536;
    float v = (c < 512) ? od[(size_t)r * 512 + c] : ctx[(size_t)r * 1024 + (c - 512)];
    x1[i] = f2bf(v);
}

// ---------- host ----------
extern "C" void kernel_launch(void* const* d_in, const int* in_sizes, int n_in,
                              void* d_out, int out_size, void* d_ws, size_t ws_size,
                              hipStream_t stream) {
    const float* output_enc = (const float*)d_in[0];
    const float* input_dec  = (const float*)d_in[1];
    const float* hidden_enc = (const float*)d_in[2];
    const float* cell_enc   = (const float*)d_in[3];
    const float* W_ih0 = (const float*)d_in[4],  *W_hh0 = (const float*)d_in[5];
    const float* b_ih0 = (const float*)d_in[6],  *b_hh0 = (const float*)d_in[7];
    const float* W_ih1 = (const float*)d_in[8],  *W_hh1 = (const float*)d_in[9];
    const float* b_ih1 = (const float*)d_in[10], *b_hh1 = (const float*)d_in[11];
    const float* W_red = (const float*)d_in[12], *b_red = (const float*)d_in[13];
    const float* W_att = (const float*)d_in[14], *b_att = (const float*)d_in[15];
    const float* v_att = (const float*)d_in[16];
    const float* W_v1  = (const float*)d_in[17], *b_v1 = (const float*)d_in[18];
    const float* W_v2  = (const float*)d_in[19], *b_v2 = (const float*)d_in[20];

    char* ws = (char*)d_ws;
    size_t off = 0;
    auto alloc = [&](size_t bytes) -> void* {
        void* p = ws + off;
        off += (bytes + 255) & ~(size_t)255;
        return p;
    };
    float*  h0buf = (float*)alloc(2 * BB * HH * 4);
    float*  h1buf = (float*)alloc(2 * BB * HH * 4);
    float*  c0    = (float*)alloc(BB * HH * 4);
    float*  c1    = (float*)alloc(BB * HH * 4);
    float*  od    = (float*)alloc((size_t)SD * BB * HH * 4);        // 3.28 MB
    ushort* od_bf = (ushort*)alloc((size_t)SD * BB * HH * 2);
    ushort* oe_bf = (ushort*)alloc((size_t)SE * BB * 1024 * 2);     // 26.2 MB
    ushort* wae   = (ushort*)alloc((size_t)AA * 1024 * 2);
    ushort* wad   = (ushort*)alloc((size_t)AA * 512 * 2);
    float*  encp  = (float*)alloc((size_t)SE * BB * AA * 4);        // 6.55 MB
    float*  decp  = (float*)alloc((size_t)SD * BB * AA * 4);
    float*  attn  = (float*)alloc((size_t)BB * SD * SE * 4);        // 2.56 MB
    float*  ctx   = (float*)alloc((size_t)SD * BB * 1024 * 4);      // 6.55 MB
    ushort* x1    = (ushort*)alloc((size_t)1600 * 1536 * 2);        // 4.9 MB
    ushort* wv1   = (ushort*)alloc((size_t)VF * 1536 * 2);          // 3.1 MB
    ushort* y1    = (ushort*)alloc((size_t)1600 * VF * 2);          // 3.3 MB
    ushort* wv2   = (ushort*)alloc((size_t)VV * 1024 * 2);          // 65.5 MB

    // --- weight / input conversions to bf16 ---
    k_cvt_flat<<<12800, 256, 0, stream>>>(output_enc, oe_bf, (long)SE * BB * 1024 / 4);
    k_cvt_strided<<<512, 256, 0, stream>>>(W_att, wae, AA, 1024, 1536, 0);
    k_cvt_strided<<<256, 256, 0, stream>>>(W_att, wad, AA, 512, 1536, 1024);
    k_cvt_flat<<<1536, 256, 0, stream>>>(W_v1, wv1, (long)VF * 1536 / 4);
    k_cvt_flat<<<32000, 256, 0, stream>>>(W_v2, wv2, (long)VV * 1024 / 4);

    // --- fold encoder state through reduce_dim ---
    k_fold<<<dim3(2, 32, 4), 256, 0, stream>>>(hidden_enc, cell_enc, W_red, b_red,
                                               h0buf, h1buf, c0, c1);

    // --- sequential 2-layer LSTM, ping-pong h buffers ---
    for (int t = 0; t < SD; t++) {
        const float* xin = input_dec + (size_t)t * BB * INW;
        float* h0i = h0buf + (t & 1) * BB * HH;
        float* h0o = h0buf + ((t + 1) & 1) * BB * HH;
        float* h1i = h1buf + (t & 1) * BB * HH;
        float* h1o = h1buf + ((t + 1) & 1) * BB * HH;
        k_lstm<<<dim3(8, 32), 256, 0, stream>>>(xin, h0i, W_ih0, W_hh0, b_ih0, b_hh0,
                                                c0, h0o, (float*)nullptr);
        k_lstm<<<dim3(8, 32), 256, 0, stream>>>(h0o, h1i, W_ih1, W_hh1, b_ih1, b_hh1,
                                                c1, h1o, od + (size_t)t * BB * HH);
    }
    // final states (after 50 steps, buffers index 0)
    k_states<<<64, 256, 0, stream>>>(h0buf, h1buf, c0, c1, (float*)d_out + (size_t)SD * BB * VV);

    // --- attention ---
    k_cvt_flat<<<800, 256, 0, stream>>>(od, od_bf, (long)SD * BB * HH / 4);
    k_gemm<false><<<dim3(200, 1), 256, 0, stream>>>(oe_bf, wae, encp, nullptr,
                                                    (const float*)nullptr, SE * BB, AA, 1024);
    k_gemm<false><<<dim3(25, 1), 256, 0, stream>>>(od_bf, wad, decp, nullptr,
                                                   b_att, SD * BB, AA, 512);
    k_scores<<<dim3(SD, BB), 256, 0, stream>>>(encp, decp, v_att, attn);
    k_context<<<dim3(32, 4, 2), 256, 0, stream>>>(attn, output_enc, ctx);

    // --- vocab MLP ---
    k_concat<<<9600, 256, 0, stream>>>(od, ctx, x1);
    k_gemm<true><<<dim3(25, 8), 256, 0, stream>>>(x1, wv1, nullptr, y1, b_v1,
                                                  1600, VF, 1536);
    k_gemm<false><<<dim3(25, 250), 256, 0, stream>>>(y1, wv2, (float*)d_out, nullptr, b_v2,
                                                     1600, VV, 1024);
    (void)in_sizes; (void)n_in; (void)out_size; (void)ws_size;
}

// Round 3
// 1669.384 us; speedup vs baseline: 2.4049x; 2.4049x over previous
//
#include <hip/hip_runtime.h>
#include <cstdint>

#define DEV __device__ __forceinline__

typedef short bfrag __attribute__((ext_vector_type(8)));   // 8 bf16 (4 VGPRs)
typedef float ffrag __attribute__((ext_vector_type(4)));   // 4 f32 acc

// ---------- constants ----------
constexpr int SE = 400, SD = 50, BB = 32;
constexpr int HH = 512, INW = 512, AA = 128;
constexpr int VF = 1024, VV = 32000;
constexpr int G4 = 2048;   // 4*H

// ---------- helpers ----------
DEV ushort f2bf(float f) {
    uint32_t u = __float_as_uint(f);
    u = (u + 0x7FFF + ((u >> 16) & 1)) >> 16;   // RNE
    return (ushort)u;
}
DEV float bf2f(ushort u) { return __uint_as_float(((uint32_t)u) << 16); }
DEV float sigm_(float x) { return 1.f / (1.f + __expf(-x)); }
DEV float tanh_(float x) { float e = __expf(2.f * x); return 1.f - 2.f / (e + 1.f); }
DEV int imin(int a, int b) { return a < b ? a : b; }
DEV int imax(int a, int b) { return a > b ? a : b; }

DEV void gload_lds16(const void* g, void* l) {
    __builtin_amdgcn_global_load_lds((const __attribute__((address_space(1))) uint32_t*)g,
                                     (__attribute__((address_space(3))) uint32_t*)l, 16, 0, 0);
}

// ---------- f32 -> bf16 converters ----------
__global__ __launch_bounds__(256) void k_cvt_flat(const float* __restrict__ s,
                                                  ushort* __restrict__ d, long n4) {
    long i = (long)blockIdx.x * 256 + threadIdx.x;
    if (i >= n4) return;
    float4 v = ((const float4*)s)[i];
    ushort4 o;
    o.x = f2bf(v.x); o.y = f2bf(v.y); o.z = f2bf(v.z); o.w = f2bf(v.w);
    ((ushort4*)d)[i] = o;
}

// strided f32 src -> strided bf16 dst (4-wide)
__global__ __launch_bounds__(256) void k_cvt_strided(const float* __restrict__ s,
                                                     ushort* __restrict__ d,
                                                     int rows, int cols, int sstride, int soff,
                                                     int dstride, int doff) {
    int i = blockIdx.x * 256 + threadIdx.x;
    int c4n = cols >> 2;
    if (i >= rows * c4n) return;
    int r = i / c4n, c = (i - r * c4n) * 4;
    float4 v = *(const float4*)(s + (size_t)r * sstride + soff + c);
    ushort4 o;
    o.x = f2bf(v.x); o.y = f2bf(v.y); o.z = f2bf(v.z); o.w = f2bf(v.w);
    *(ushort4*)(d + (size_t)r * dstride + doff + c) = o;
}

// ---------- bias sums ----------
__global__ __launch_bounds__(256) void k_bsum(const float* __restrict__ bi0, const float* __restrict__ bh0,
                                              const float* __restrict__ bi1, const float* __restrict__ bh1,
                                              float* __restrict__ bsum0, float* __restrict__ bsum1) {
    int i = blockIdx.x * 256 + threadIdx.x;
    if (i >= G4) return;
    bsum0[i] = bi0[i] + bh0[i];
    bsum1[i] = bi1[i] + bh1[i];
}

// ---------- fold encoder state + reduce_dim ----------
// grid: (2 jchunk, 32 b, 4 z) z: bit0 = layer, bit1 = is_cell
__global__ __launch_bounds__(256) void k_fold(const float* __restrict__ hid,
                                              const float* __restrict__ cel,
                                              const float* __restrict__ W_red,
                                              const float* __restrict__ b_red,
                                              float* __restrict__ h0m,
                                              float* __restrict__ c0, float* __restrict__ c1,
                                              ushort* __restrict__ AB) {   // [2][32][1024]
    int tid = threadIdx.x;
    int j = blockIdx.x * 256 + tid;
    int b = blockIdx.y;
    int l = blockIdx.z & 1;
    bool is_c = blockIdx.z >> 1;
    const float* src = is_c ? cel : hid;
    __shared__ float xs[1024];
    for (int i = tid; i < 512; i += 256) {
        xs[i]       = src[((size_t)l * BB + b) * HH + i];
        xs[512 + i] = src[((size_t)(l + 2) * BB + b) * HH + i];
    }
    __syncthreads();
    const float4* w  = (const float4*)(W_red + (size_t)j * 1024);
    const float4* xv = (const float4*)xs;
    float acc = b_red[j];
    for (int k = 0; k < 256; k++) {
        float4 a = w[k], x = xv[k];
        acc += a.x * x.x + a.y * x.y + a.z * x.z + a.w * x.w;
    }
    if (is_c) {
        (l ? c1 : c0)[(size_t)b * HH + j] = acc;
    } else {
        if (l == 0) {
            h0m[(size_t)b * HH + j] = acc;
            AB[(size_t)32 * 1024 + (size_t)b * 1024 + j] = f2bf(acc);   // parity-1, h0 half
        } else {
            AB[(size_t)b * 1024 + 512 + j] = f2bf(acc);                 // parity-0, h1 half
        }
    }
}

// ---------- pipelined LSTM cell: layer0[t0] and layer1[t1] in one launch ----------
// grid (32 jb, 2 layer), 256 threads = 4 waves; wave q = gate q, 16 cols each
__global__ __launch_bounds__(256) void k_cell(const ushort* __restrict__ Aprev,  // [32][1024]
                                              const ushort* __restrict__ W0,     // [2048][512]
                                              const ushort* __restrict__ W1,     // [2048][1024]
                                              const float* __restrict__ gx,      // [32][2048] (layer0, incl biases)
                                              const float* __restrict__ bsum1,   // [2048]
                                              float* __restrict__ c0, float* __restrict__ c1,
                                              float* __restrict__ h0m,
                                              float* __restrict__ od1,           // [32][512] f32 (h1 of t1)
                                              ushort* __restrict__ od1_bf,
                                              ushort* __restrict__ ABdst,        // [32][1024]
                                              int do_l0, int do_l1) {
    const int layer = blockIdx.y;
    if (layer == 0 && !do_l0) return;
    if (layer == 1 && !do_l1) return;
    const int jb = blockIdx.x;
    const int tid = threadIdx.x, wave = tid >> 6, lane = tid & 63;
    const int lr = lane & 15, lk = lane >> 4;
    const int K = layer ? 1024 : 512;
    const ushort* Wm = layer ? W1 : W0;
    const int wstride = layer ? 1024 : 512;
    const int n0 = wave * 512 + jb * 16;

    const ushort* arow0 = Aprev + (size_t)lr * 1024;
    const ushort* arow1 = Aprev + (size_t)(16 + lr) * 1024;
    const ushort* wrow  = Wm + (size_t)(n0 + lr) * wstride;

    ffrag acc0 = {0.f, 0.f, 0.f, 0.f}, acc1 = {0.f, 0.f, 0.f, 0.f};
    #pragma unroll 4
    for (int k0 = 0; k0 < K; k0 += 32) {
        bfrag a0 = *(const bfrag*)(arow0 + k0 + lk * 8);
        bfrag a1 = *(const bfrag*)(arow1 + k0 + lk * 8);
        bfrag bw = *(const bfrag*)(wrow + k0 + lk * 8);
        acc0 = __builtin_amdgcn_mfma_f32_16x16x32_bf16(a0, bw, acc0, 0, 0, 0);
        acc1 = __builtin_amdgcn_mfma_f32_16x16x32_bf16(a1, bw, acc1, 0, 0, 0);
    }

    __shared__ float gl[4][32][16];
    #pragma unroll
    for (int r = 0; r < 4; r++) {
        gl[wave][lk * 4 + r][lr]      = acc0[r];
        gl[wave][16 + lk * 4 + r][lr] = acc1[r];
    }
    __syncthreads();

    for (int e = tid; e < 512; e += 256) {
        int b = e >> 4, jj = e & 15;
        int j = jb * 16 + jj;
        float gi = gl[0][b][jj], gf = gl[1][b][jj], gg = gl[2][b][jj], go = gl[3][b][jj];
        if (layer == 0) {
            const float* gxp = gx + (size_t)b * G4;
            gi += gxp[j]; gf += gxp[512 + j]; gg += gxp[1024 + j]; go += gxp[1536 + j];
        } else {
            gi += bsum1[j]; gf += bsum1[512 + j]; gg += bsum1[1024 + j]; go += bsum1[1536 + j];
        }
        float* cc = layer ? c1 : c0;
        size_t ci = (size_t)b * HH + j;
        float cn = sigm_(gf) * cc[ci] + sigm_(gi) * tanh_(gg);
        cc[ci] = cn;
        float hn = sigm_(go) * tanh_(cn);
        ushort hb = f2bf(hn);
        if (layer == 0) {
            h0m[ci] = hn;
            ABdst[(size_t)b * 1024 + j] = hb;
        } else {
            od1[ci] = hn;
            od1_bf[ci] = hb;
            ABdst[(size_t)b * 1024 + 512 + j] = hb;
        }
    }
}

// ---------- write final hidden/cell states ----------
__global__ __launch_bounds__(256) void k_states(const float* __restrict__ h0,
                                                const float* __restrict__ h1,
                                                const float* __restrict__ c0,
                                                const float* __restrict__ c1,
                                                float* __restrict__ out) {
    int i = blockIdx.x * 256 + threadIdx.x;
    if (i >= BB * HH) return;
    out[i]               = h0[i];
    out[BB * HH + i]     = h1[i];
    out[2 * BB * HH + i] = c0[i];
    out[3 * BB * HH + i] = c1[i];
}

// ---------- 128x128x32 bf16 MFMA GEMM: C[M,N] = X[M,K] @ W[N,K]^T + bias ----------
// 4 waves, wave (wm,wn) owns 64x64 = 4x4 frags. Flat grid + bijective XCD swizzle,
// M-tile fastest so same-N blocks co-reside on one XCD (W-panel L2 reuse).
template <int OUT_BF16>
__global__ __launch_bounds__(256) void k_gemm128(const ushort* __restrict__ X,
                                                 const ushort* __restrict__ W,
                                                 float* __restrict__ Cf,
                                                 ushort* __restrict__ Cb,
                                                 const float* __restrict__ bias,
                                                 int M, int N, int K, int nmt) {
    __shared__ ushort As[128 * 32];
    __shared__ ushort Bs[128 * 32];
    const int tid = threadIdx.x;
    const int wave = tid >> 6, lane = tid & 63;
    const int lr = lane & 15, lk = lane >> 4;
    const int wm = wave >> 1, wn = wave & 1;

    // bijective XCD swizzle (m204)
    int nwg = gridDim.x, flat = blockIdx.x;
    int q = nwg >> 3, r = nwg & 7;
    int xcd = flat & 7, idx = flat >> 3;
    int wg = (xcd < r ? xcd * (q + 1) : r * (q + 1) + (xcd - r) * q) + idx;
    const int m0 = (wg % nmt) * 128, n0 = (wg / nmt) * 128;

    ffrag acc[4][4];
    #pragma unroll
    for (int i = 0; i < 4; i++)
        #pragma unroll
        for (int j = 0; j < 4; j++) acc[i][j] = (ffrag){0.f, 0.f, 0.f, 0.f};

    // staging: pass p covers rows p*64 + wave*16 + (lane>>2), col (lane&3)*8
    const int srow = wave * 16 + (lane >> 2);
    const int scol = (lane & 3) * 8;
    const int ar0 = imin(m0 + srow, M - 1);
    const int ar1 = imin(m0 + 64 + srow, M - 1);
    const ushort* Agp0 = X + (size_t)ar0 * K + scol;
    const ushort* Agp1 = X + (size_t)ar1 * K + scol;
    const ushort* Bgp0 = W + (size_t)(n0 + srow) * K + scol;
    const ushort* Bgp1 = W + (size_t)(n0 + 64 + srow) * K + scol;
    ushort* AsW0 = As + wave * 512;
    ushort* AsW1 = As + 2048 + wave * 512;
    ushort* BsW0 = Bs + wave * 512;
    ushort* BsW1 = Bs + 2048 + wave * 512;

    for (int k0 = 0; k0 < K; k0 += 32) {
        gload_lds16(Agp0 + k0, AsW0);
        gload_lds16(Agp1 + k0, AsW1);
        gload_lds16(Bgp0 + k0, BsW0);
        gload_lds16(Bgp1 + k0, BsW1);
        __syncthreads();
        bfrag a[4], bfr[4];
        #pragma unroll
        for (int mf = 0; mf < 4; mf++)
            a[mf] = *(const bfrag*)&As[(wm * 64 + mf * 16 + lr) * 32 + lk * 8];
        #pragma unroll
        for (int nf = 0; nf < 4; nf++)
            bfr[nf] = *(const bfrag*)&Bs[(wn * 64 + nf * 16 + lr) * 32 + lk * 8];
        #pragma unroll
        for (int mf = 0; mf < 4; mf++)
            #pragma unroll
            for (int nf = 0; nf < 4; nf++)
                acc[mf][nf] = __builtin_amdgcn_mfma_f32_16x16x32_bf16(a[mf], bfr[nf], acc[mf][nf], 0, 0, 0);
        __syncthreads();
    }

    #pragma unroll
    for (int mf = 0; mf < 4; mf++) {
        int rbase = m0 + wm * 64 + mf * 16 + lk * 4;
        #pragma unroll
        for (int nf = 0; nf < 4; nf++) {
            int cc = n0 + wn * 64 + nf * 16 + lr;
            float bv = bias ? bias[cc] : 0.f;
            #pragma unroll
            for (int rr = 0; rr < 4; rr++) {
                int row = rbase + rr;
                if (row < M) {
                    float v = acc[mf][nf][rr] + bv;
                    if (OUT_BF16) Cb[(size_t)row * N + cc] = f2bf(v);
                    else          Cf[(size_t)row * N + cc] = v;
                }
            }
        }
    }
}

// ---------- attention scores + softmax over encoder axis ----------
__global__ __launch_bounds__(256) void k_scores(const float* __restrict__ encp,  // [400][32][128]
                                                const float* __restrict__ decp,  // [50][32][128]
                                                const float* __restrict__ v_att, // [128]
                                                float* __restrict__ attn) {      // [32][50][400]
    int t = blockIdx.x, b = blockIdx.y, tid = threadIdx.x;
    __shared__ float dp[128], vv[128];
    __shared__ float e_lds[400];
    __shared__ float red[8];
    if (tid < 128) {
        dp[tid] = decp[((size_t)t * BB + b) * AA + tid];
        vv[tid] = v_att[tid];
    }
    __syncthreads();
    for (int s = tid; s < SE; s += 256) {
        const float* ep = encp + ((size_t)s * BB + b) * AA;
        float a0 = 0.f;
        #pragma unroll 4
        for (int a = 0; a < AA; a++) a0 += vv[a] * tanh_(ep[a] + dp[a]);
        e_lds[s] = a0;
    }
    __syncthreads();
    float m = -1e30f;
    for (int s = tid; s < SE; s += 256) m = fmaxf(m, e_lds[s]);
    #pragma unroll
    for (int o = 32; o > 0; o >>= 1) m = fmaxf(m, __shfl_xor(m, o));
    if ((tid & 63) == 0) red[tid >> 6] = m;
    __syncthreads();
    m = fmaxf(fmaxf(red[0], red[1]), fmaxf(red[2], red[3]));
    float sum = 0.f;
    for (int s = tid; s < SE; s += 256) {
        float ex = __expf(e_lds[s] - m);
        e_lds[s] = ex;
        sum += ex;
    }
    #pragma unroll
    for (int o = 32; o > 0; o >>= 1) sum += __shfl_xor(sum, o);
    if ((tid & 63) == 0) red[4 + (tid >> 6)] = sum;
    __syncthreads();
    float inv = 1.f / (red[4] + red[5] + red[6] + red[7]);
    for (int s = tid; s < SE; s += 256)
        attn[((size_t)b * SD + t) * SE + s] = e_lds[s] * inv;
}

// ---------- context = attn^T @ output_enc (bf16 enc) ----------
// grid: (32 b, 4 nchunk, 2 thalf)
__global__ __launch_bounds__(256) void k_context(const float* __restrict__ attn,   // [32][50][400]
                                                 const ushort* __restrict__ oe_bf, // [400][32][1024]
                                                 float* __restrict__ ctx) {        // [50][32][1024]
    int b = blockIdx.x, nc = blockIdx.y, th = blockIdx.z, tid = threadIdx.x;
    __shared__ float at[25][400];
    const float* ap = attn + ((size_t)b * SD + th * 25) * SE;
    for (int i = tid; i < 25 * 400; i += 256) at[i / 400][i % 400] = ap[i];
    __syncthreads();
    int n = nc * 256 + tid;
    float acc[25];
    #pragma unroll
    for (int i = 0; i < 25; i++) acc[i] = 0.f;
    for (int s = 0; s < SE; s++) {
        float v = bf2f(oe_bf[((size_t)s * BB + b) * 1024 + n]);
        #pragma unroll
        for (int tt = 0; tt < 25; tt++) acc[tt] += at[tt][s] * v;
    }
    #pragma unroll
    for (int tt = 0; tt < 25; tt++)
        ctx[(((size_t)(th * 25 + tt)) * BB + b) * 1024 + n] = acc[tt];
}

// ---------- concat [od_bf, ctx] -> bf16 X1 [1600][1536] ----------
__global__ __launch_bounds__(256) void k_concat(const ushort* __restrict__ od_bf, // [1600][512]
                                                const float* __restrict__ ctx,    // [1600][1024]
                                                ushort* __restrict__ x1) {
    int i = blockIdx.x * 256 + threadIdx.x;
    if (i >= 1600 * 384) return;
    int rr = i / 384, c4 = (i - rr * 384) * 4;
    ushort4 o;
    if (c4 < 512) {
        o = *(const ushort4*)(od_bf + (size_t)rr * 512 + c4);
    } else {
        float4 v = *(const float4*)(ctx + (size_t)rr * 1024 + (c4 - 512));
        o.x = f2bf(v.x); o.y = f2bf(v.y); o.z = f2bf(v.z); o.w = f2bf(v.w);
    }
    *(ushort4*)(x1 + (size_t)rr * 1536 + c4) = o;
}

// ---------- host ----------
extern "C" void kernel_launch(void* const* d_in, const int* in_sizes, int n_in,
                              void* d_out, int out_size, void* d_ws, size_t ws_size,
                              hipStream_t stream) {
    const float* output_enc = (const float*)d_in[0];
    const float* input_dec  = (const float*)d_in[1];
    const float* hidden_enc = (const float*)d_in[2];
    const float* cell_enc   = (const float*)d_in[3];
    const float* W_ih0 = (const float*)d_in[4],  *W_hh0 = (const float*)d_in[5];
    const float* b_ih0 = (const float*)d_in[6],  *b_hh0 = (const float*)d_in[7];
    const float* W_ih1 = (const float*)d_in[8],  *W_hh1 = (const float*)d_in[9];
    const float* b_ih1 = (const float*)d_in[10], *b_hh1 = (const float*)d_in[11];
    const float* W_red = (const float*)d_in[12], *b_red = (const float*)d_in[13];
    const float* W_att = (const float*)d_in[14], *b_att = (const float*)d_in[15];
    const float* v_att = (const float*)d_in[16];
    const float* W_v1  = (const float*)d_in[17], *b_v1 = (const float*)d_in[18];
    const float* W_v2  = (const float*)d_in[19], *b_v2 = (const float*)d_in[20];

    char* ws = (char*)d_ws;
    size_t off = 0;
    auto alloc = [&](size_t bytes) -> void* {
        void* p = ws + off;
        off += (bytes + 255) & ~(size_t)255;
        return p;
    };
    float*  h0m    = (float*)alloc(BB * HH * 4);
    float*  c0     = (float*)alloc(BB * HH * 4);
    float*  c1     = (float*)alloc(BB * HH * 4);
    ushort* AB     = (ushort*)alloc(2 * BB * 1024 * 2);               // [2][32][1024]
    float*  od     = (float*)alloc((size_t)SD * BB * HH * 4);         // 3.3 MB
    ushort* od_bf  = (ushort*)alloc((size_t)SD * BB * HH * 2);
    ushort* xd_bf  = (ushort*)alloc((size_t)SD * BB * INW * 2);       // 1.6 MB
    ushort* wih0b  = (ushort*)alloc((size_t)G4 * 512 * 2);            // 2 MB
    ushort* whh0b  = (ushort*)alloc((size_t)G4 * 512 * 2);            // 2 MB
    ushort* w1cat  = (ushort*)alloc((size_t)G4 * 1024 * 2);           // 4 MB
    float*  bsum0  = (float*)alloc(G4 * 4);
    float*  bsum1  = (float*)alloc(G4 * 4);
    float*  gx0    = (float*)alloc((size_t)SD * BB * G4 * 4);         // 13.1 MB
    ushort* oe_bf  = (ushort*)alloc((size_t)SE * BB * 1024 * 2);      // 26.2 MB
    ushort* wae    = (ushort*)alloc((size_t)AA * 1024 * 2);
    ushort* wad    = (ushort*)alloc((size_t)AA * 512 * 2);
    float*  encp   = (float*)alloc((size_t)SE * BB * AA * 4);         // 6.6 MB
    float*  decp   = (float*)alloc((size_t)SD * BB * AA * 4);
    float*  attn   = (float*)alloc((size_t)BB * SD * SE * 4);         // 2.6 MB
    float*  ctx    = (float*)alloc((size_t)SD * BB * 1024 * 4);       // 6.6 MB
    ushort* x1     = (ushort*)alloc((size_t)1600 * 1536 * 2);         // 4.9 MB
    ushort* wv1    = (ushort*)alloc((size_t)VF * 1536 * 2);           // 3.1 MB
    ushort* y1     = (ushort*)alloc((size_t)1600 * VF * 2);           // 3.3 MB
    ushort* wv2    = (ushort*)alloc((size_t)VV * 1024 * 2);           // 65.5 MB

    // --- conversions ---
    k_cvt_flat<<<800, 256, 0, stream>>>(input_dec, xd_bf, (long)SD * BB * INW / 4);
    k_cvt_flat<<<12800, 256, 0, stream>>>(output_enc, oe_bf, (long)SE * BB * 1024 / 4);
    k_cvt_flat<<<1024, 256, 0, stream>>>(W_ih0, wih0b, (long)G4 * 512 / 4);
    k_cvt_flat<<<1024, 256, 0, stream>>>(W_hh0, whh0b, (long)G4 * 512 / 4);
    k_cvt_strided<<<1024, 256, 0, stream>>>(W_ih1, w1cat, G4, 512, 512, 0, 1024, 0);
    k_cvt_strided<<<1024, 256, 0, stream>>>(W_hh1, w1cat, G4, 512, 512, 0, 1024, 512);
    k_cvt_strided<<<128, 256, 0, stream>>>(W_att, wae, AA, 1024, 1536, 0, 1024, 0);
    k_cvt_strided<<<64, 256, 0, stream>>>(W_att, wad, AA, 512, 1536, 1024, 512, 0);
    k_cvt_flat<<<1536, 256, 0, stream>>>(W_v1, wv1, (long)VF * 1536 / 4);
    k_cvt_flat<<<32000, 256, 0, stream>>>(W_v2, wv2, (long)VV * 1024 / 4);
    k_bsum<<<8, 256, 0, stream>>>(b_ih0, b_hh0, b_ih1, b_hh1, bsum0, bsum1);

    // --- fold encoder state through reduce_dim (also seeds bf16 AB halves) ---
    k_fold<<<dim3(2, 32, 4), 256, 0, stream>>>(hidden_enc, cell_enc, W_red, b_red,
                                               h0m, c0, c1, AB);

    // --- precompute layer-0 x-path gates for all timesteps ---
    k_gemm128<0><<<13 * 16, 256, 0, stream>>>(xd_bf, wih0b, gx0, nullptr, bsum0,
                                              SD * BB, G4, 512, 13);

    // --- pipelined LSTM: launch i = layer0[i] || layer1[i-1] ---
    for (int i = 0; i <= SD; i++) {
        const ushort* Aprev = AB + (size_t)((i + 1) & 1) * BB * 1024;
        ushort* ABdst = AB + (size_t)(i & 1) * BB * 1024;
        int t1c = (i > 0) ? (i - 1) : 0;
        k_cell<<<dim3(32, 2), 256, 0, stream>>>(Aprev, whh0b, w1cat,
                                                gx0 + (size_t)i * BB * G4, bsum1,
                                                c0, c1, h0m,
                                                od + (size_t)t1c * BB * HH,
                                                od_bf + (size_t)t1c * BB * HH,
                                                ABdst, (int)(i < SD), (int)(i > 0));
    }
    k_states<<<64, 256, 0, stream>>>(h0m, od + (size_t)(SD - 1) * BB * HH, c0, c1,
                                     (float*)d_out + (size_t)SD * BB * VV);

    // --- attention ---
    k_gemm128<0><<<100, 256, 0, stream>>>(oe_bf, wae, encp, nullptr,
                                          (const float*)nullptr, SE * BB, AA, 1024, 100);
    k_gemm128<0><<<13, 256, 0, stream>>>(od_bf, wad, decp, nullptr,
                                         b_att, SD * BB, AA, 512, 13);
    k_scores<<<dim3(SD, BB), 256, 0, stream>>>(encp, decp, v_att, attn);
    k_context<<<dim3(32, 4, 2), 256, 0, stream>>>(attn, oe_bf, ctx);

    // --- vocab MLP ---
    k_concat<<<2400, 256, 0, stream>>>(od_bf, ctx, x1);
    k_gemm128<1><<<13 * 8, 256, 0, stream>>>(x1, wv1, nullptr, y1, b_v1,
                                             1600, VF, 1536, 13);
    k_gemm128<0><<<13 * 250, 256, 0, stream>>>(y1, wv2, (float*)d_out, nullptr, b_v2,
                                               1600, VV, 1024, 13);
    (void)in_sizes; (void)n_in; (void)out_size; (void)ws_size;
}

// Round 5
// 1631.052 us; speedup vs baseline: 2.4614x; 1.0235x over previous
//
#include <hip/hip_runtime.h>
#include <cstdint>

#define DEV __device__ __forceinline__

typedef short bfrag __attribute__((ext_vector_type(8)));   // 8 bf16 (4 VGPRs)
typedef float ffrag __attribute__((ext_vector_type(4)));   // 4 f32 acc

// ---------- constants ----------
constexpr int SE = 400, SD = 50, BB = 32;
constexpr int HH = 512, INW = 512, AA = 128;
constexpr int VF = 1024, VV = 32000;
constexpr int G4 = 2048;   // 4*H

// ---------- helpers ----------
DEV ushort f2bf(float f) {
    uint32_t u = __float_as_uint(f);
    u = (u + 0x7FFF + ((u >> 16) & 1)) >> 16;   // RNE
    return (ushort)u;
}
DEV float bf2f(ushort u) { return __uint_as_float(((uint32_t)u) << 16); }
DEV float sigm_(float x) { return 1.f / (1.f + __expf(-x)); }
DEV float tanh_(float x) { float e = __expf(2.f * x); return 1.f - 2.f / (e + 1.f); }
DEV int imin(int a, int b) { return a < b ? a : b; }

DEV void gload_lds16(const void* g, void* l) {
    __builtin_amdgcn_global_load_lds((const __attribute__((address_space(1))) uint32_t*)g,
                                     (__attribute__((address_space(3))) uint32_t*)l, 16, 0, 0);
}

// ---------- fused f32 -> bf16 converters (segment tables) ----------
struct CvtFlatTab {
    const float* src[6];
    ushort* dst[6];
    int blk_end[6];   // cumulative block counts; each block = 1024 elems (256 thr x4)
    int nseg;
};
__global__ __launch_bounds__(256) void k_cvt_multi(CvtFlatTab t) {
    int blk = blockIdx.x, seg = 0;
    while (seg < t.nseg - 1 && blk >= t.blk_end[seg]) seg++;
    int base = seg ? t.blk_end[seg - 1] : 0;
    long i = (long)(blk - base) * 256 + threadIdx.x;   // float4 index
    float4 v = ((const float4*)t.src[seg])[i];
    ushort4 o;
    o.x = f2bf(v.x); o.y = f2bf(v.y); o.z = f2bf(v.z); o.w = f2bf(v.w);
    ((ushort4*)t.dst[seg])[i] = o;
}

struct CvtStrTab {
    const float* src[4];
    ushort* dst[4];
    int ss[4], so[4], ds[4], dofs[4], c4n[4];   // strides/offsets, cols/4
    int blk_end[4];
    int nseg;
};
__global__ __launch_bounds__(256) void k_cvt_str_multi(CvtStrTab t) {
    int blk = blockIdx.x, seg = 0;
    while (seg < t.nseg - 1 && blk >= t.blk_end[seg]) seg++;
    int base = seg ? t.blk_end[seg - 1] : 0;
    int i = (blk - base) * 256 + threadIdx.x;
    int c4n = t.c4n[seg];
    int r = i / c4n, c = (i - r * c4n) * 4;
    float4 v = *(const float4*)(t.src[seg] + (size_t)r * t.ss[seg] + t.so[seg] + c);
    ushort4 o;
    o.x = f2bf(v.x); o.y = f2bf(v.y); o.z = f2bf(v.z); o.w = f2bf(v.w);
    *(ushort4*)(t.dst[seg] + (size_t)r * t.ds[seg] + t.dofs[seg] + c) = o;
}

// ---------- bias sums ----------
__global__ __launch_bounds__(256) void k_bsum(const float* __restrict__ bi0, const float* __restrict__ bh0,
                                              const float* __restrict__ bi1, const float* __restrict__ bh1,
                                              float* __restrict__ bsum0, float* __restrict__ bsum1) {
    int i = blockIdx.x * 256 + threadIdx.x;
    if (i >= G4) return;
    bsum0[i] = bi0[i] + bh0[i];
    bsum1[i] = bi1[i] + bh1[i];
}

// ---------- fold encoder state + reduce_dim ----------
__global__ __launch_bounds__(256) void k_fold(const float* __restrict__ hid,
                                              const float* __restrict__ cel,
                                              const float* __restrict__ W_red,
                                              const float* __restrict__ b_red,
                                              float* __restrict__ h0m,
                                              float* __restrict__ c0, float* __restrict__ c1,
                                              ushort* __restrict__ AB) {   // [2][32][1024]
    int tid = threadIdx.x;
    int j = blockIdx.x * 256 + tid;
    int b = blockIdx.y;
    int l = blockIdx.z & 1;
    bool is_c = blockIdx.z >> 1;
    const float* src = is_c ? cel : hid;
    __shared__ float xs[1024];
    for (int i = tid; i < 512; i += 256) {
        xs[i]       = src[((size_t)l * BB + b) * HH + i];
        xs[512 + i] = src[((size_t)(l + 2) * BB + b) * HH + i];
    }
    __syncthreads();
    const float4* w  = (const float4*)(W_red + (size_t)j * 1024);
    const float4* xv = (const float4*)xs;
    float acc = b_red[j];
    for (int k = 0; k < 256; k++) {
        float4 a = w[k], x = xv[k];
        acc += a.x * x.x + a.y * x.y + a.z * x.z + a.w * x.w;
    }
    if (is_c) {
        (l ? c1 : c0)[(size_t)b * HH + j] = acc;
    } else {
        if (l == 0) {
            h0m[(size_t)b * HH + j] = acc;
            AB[(size_t)32 * 1024 + (size_t)b * 1024 + j] = f2bf(acc);   // parity-1, h0 half
        } else {
            AB[(size_t)b * 1024 + 512 + j] = f2bf(acc);                 // parity-0, h1 half
        }
    }
}

// ---------- pipelined LSTM cell: layer0[t0] and layer1[t1] in one launch ----------
__global__ __launch_bounds__(256) void k_cell(const ushort* __restrict__ Aprev,  // [32][1024]
                                              const ushort* __restrict__ W0,     // [2048][512]
                                              const ushort* __restrict__ W1,     // [2048][1024]
                                              const float* __restrict__ gx,      // [32][2048]
                                              const float* __restrict__ bsum1,   // [2048]
                                              float* __restrict__ c0, float* __restrict__ c1,
                                              float* __restrict__ h0m,
                                              float* __restrict__ od1,           // [32][512] f32
                                              ushort* __restrict__ od1_bf,
                                              ushort* __restrict__ x1row,        // x1 + t1*32*1536
                                              ushort* __restrict__ ABdst,        // [32][1024]
                                              int do_l0, int do_l1) {
    const int layer = blockIdx.y;
    if (layer == 0 && !do_l0) return;
    if (layer == 1 && !do_l1) return;
    const int jb = blockIdx.x;
    const int tid = threadIdx.x, wave = tid >> 6, lane = tid & 63;
    const int lr = lane & 15, lk = lane >> 4;
    const int K = layer ? 1024 : 512;
    const ushort* Wm = layer ? W1 : W0;
    const int wstride = layer ? 1024 : 512;
    const int n0 = wave * 512 + jb * 16;

    const ushort* arow0 = Aprev + (size_t)lr * 1024;
    const ushort* arow1 = Aprev + (size_t)(16 + lr) * 1024;
    const ushort* wrow  = Wm + (size_t)(n0 + lr) * wstride;

    ffrag acc0 = {0.f, 0.f, 0.f, 0.f}, acc1 = {0.f, 0.f, 0.f, 0.f};
    #pragma unroll 4
    for (int k0 = 0; k0 < K; k0 += 32) {
        bfrag a0 = *(const bfrag*)(arow0 + k0 + lk * 8);
        bfrag a1 = *(const bfrag*)(arow1 + k0 + lk * 8);
        bfrag bw = *(const bfrag*)(wrow + k0 + lk * 8);
        acc0 = __builtin_amdgcn_mfma_f32_16x16x32_bf16(a0, bw, acc0, 0, 0, 0);
        acc1 = __builtin_amdgcn_mfma_f32_16x16x32_bf16(a1, bw, acc1, 0, 0, 0);
    }

    __shared__ float gl[4][32][16];
    #pragma unroll
    for (int r = 0; r < 4; r++) {
        gl[wave][lk * 4 + r][lr]      = acc0[r];
        gl[wave][16 + lk * 4 + r][lr] = acc1[r];
    }
    __syncthreads();

    for (int e = tid; e < 512; e += 256) {
        int b = e >> 4, jj = e & 15;
        int j = jb * 16 + jj;
        float gi = gl[0][b][jj], gf = gl[1][b][jj], gg = gl[2][b][jj], go = gl[3][b][jj];
        if (layer == 0) {
            const float* gxp = gx + (size_t)b * G4;
            gi += gxp[j]; gf += gxp[512 + j]; gg += gxp[1024 + j]; go += gxp[1536 + j];
        } else {
            gi += bsum1[j]; gf += bsum1[512 + j]; gg += bsum1[1024 + j]; go += bsum1[1536 + j];
        }
        float* cc = layer ? c1 : c0;
        size_t ci = (size_t)b * HH + j;
        float cn = sigm_(gf) * cc[ci] + sigm_(gi) * tanh_(gg);
        cc[ci] = cn;
        float hn = sigm_(go) * tanh_(cn);
        ushort hb = f2bf(hn);
        if (layer == 0) {
            h0m[ci] = hn;
            ABdst[(size_t)b * 1024 + j] = hb;
        } else {
            od1[ci] = hn;
            od1_bf[ci] = hb;
            x1row[(size_t)b * 1536 + j] = hb;     // left half of vocab-MLP input
            ABdst[(size_t)b * 1024 + 512 + j] = hb;
        }
    }
}

// ---------- write final hidden/cell states ----------
__global__ __launch_bounds__(256) void k_states(const float* __restrict__ h0,
                                                const float* __restrict__ h1,
                                                const float* __restrict__ c0,
                                                const float* __restrict__ c1,
                                                float* __restrict__ out) {
    int i = blockIdx.x * 256 + threadIdx.x;
    if (i >= BB * HH) return;
    out[i]               = h0[i];
    out[BB * HH + i]     = h1[i];
    out[2 * BB * HH + i] = c0[i];
    out[3 * BB * HH + i] = c1[i];
}

// ---------- 128x128x32 bf16 MFMA GEMM, 2-phase double-buffered (T3-min) ----------
// C[M,N] = X[M,K] @ W[N,K]^T + bias. 4 waves, wave owns 64x64 (4x4 frags).
// Loop: STAGE(buf^1, t+1) -> ds_read(buf) -> MFMA -> syncthreads (vmcnt drain = tail only).
template <int OUT_BF16>
__global__ __launch_bounds__(256) void k_gemm128(const ushort* __restrict__ X,
                                                 const ushort* __restrict__ W,
                                                 float* __restrict__ Cf,
                                                 ushort* __restrict__ Cb,
                                                 const float* __restrict__ bias,
                                                 int M, int N, int K, int nmt) {
    __shared__ ushort As[2][4096];   // [buf][128*32]
    __shared__ ushort Bs[2][4096];
    const int tid = threadIdx.x;
    const int wave = tid >> 6, lane = tid & 63;
    const int lr = lane & 15, lk = lane >> 4;
    const int wm = wave >> 1, wn = wave & 1;

    // bijective XCD swizzle (m204)
    int nwg = gridDim.x, flat = blockIdx.x;
    int q = nwg >> 3, r = nwg & 7;
    int xcd = flat & 7, idx = flat >> 3;
    int wg = (xcd < r ? xcd * (q + 1) : r * (q + 1) + (xcd - r) * q) + idx;
    const int m0 = (wg % nmt) * 128, n0 = (wg / nmt) * 128;

    ffrag acc[4][4];
    #pragma unroll
    for (int i = 0; i < 4; i++)
        #pragma unroll
        for (int j = 0; j < 4; j++) acc[i][j] = (ffrag){0.f, 0.f, 0.f, 0.f};

    const int srow = wave * 16 + (lane >> 2);
    const int scol = (lane & 3) * 8;
    const int ar0 = imin(m0 + srow, M - 1);
    const int ar1 = imin(m0 + 64 + srow, M - 1);
    const ushort* Agp0 = X + (size_t)ar0 * K + scol;
    const ushort* Agp1 = X + (size_t)ar1 * K + scol;
    const ushort* Bgp0 = W + (size_t)(n0 + srow) * K + scol;
    const ushort* Bgp1 = W + (size_t)(n0 + 64 + srow) * K + scol;

    auto stage = [&](int buf, int k0) {
        ushort* AsW = As[buf] + wave * 512;
        ushort* BsW = Bs[buf] + wave * 512;
        gload_lds16(Agp0 + k0, AsW);
        gload_lds16(Agp1 + k0, AsW + 2048);
        gload_lds16(Bgp0 + k0, BsW);
        gload_lds16(Bgp1 + k0, BsW + 2048);
    };
    auto compute = [&](int buf) {
        bfrag a[4], bfr[4];
        #pragma unroll
        for (int mf = 0; mf < 4; mf++)
            a[mf] = *(const bfrag*)&As[buf][(wm * 64 + mf * 16 + lr) * 32 + lk * 8];
        #pragma unroll
        for (int nf = 0; nf < 4; nf++)
            bfr[nf] = *(const bfrag*)&Bs[buf][(wn * 64 + nf * 16 + lr) * 32 + lk * 8];
        #pragma unroll
        for (int mf = 0; mf < 4; mf++)
            #pragma unroll
            for (int nf = 0; nf < 4; nf++)
                acc[mf][nf] = __builtin_amdgcn_mfma_f32_16x16x32_bf16(a[mf], bfr[nf], acc[mf][nf], 0, 0, 0);
    };

    const int nt = K >> 5;
    stage(0, 0);
    __syncthreads();
    int cur = 0;
    for (int t = 0; t < nt - 1; ++t) {
        stage(cur ^ 1, (t + 1) << 5);   // prefetch next tile (latency hidden under compute)
        compute(cur);
        __syncthreads();                // vmcnt(0)+lgkmcnt(0)+barrier: next tile ready
        cur ^= 1;
    }
    compute(cur);

    #pragma unroll
    for (int mf = 0; mf < 4; mf++) {
        int rbase = m0 + wm * 64 + mf * 16 + lk * 4;
        #pragma unroll
        for (int nf = 0; nf < 4; nf++) {
            int cc = n0 + wn * 64 + nf * 16 + lr;
            float bv = bias ? bias[cc] : 0.f;
            #pragma unroll
            for (int rr = 0; rr < 4; rr++) {
                int row = rbase + rr;
                if (row < M) {
                    float v = acc[mf][nf][rr] + bv;
                    if (OUT_BF16) Cb[(size_t)row * N + cc] = f2bf(v);
                    else          Cf[(size_t)row * N + cc] = v;
                }
            }
        }
    }
}

// ---------- attention scores + softmax over encoder axis ----------
__global__ __launch_bounds__(256) void k_scores(const float* __restrict__ encp,  // [400][32][128]
                                                const float* __restrict__ decp,  // [50][32][128]
                                                const float* __restrict__ v_att, // [128]
                                                float* __restrict__ attn) {      // [32][50][400]
    int t = blockIdx.x, b = blockIdx.y, tid = threadIdx.x;
    __shared__ float dp[128], vv[128];
    __shared__ float e_lds[400];
    __shared__ float red[8];
    if (tid < 128) {
        dp[tid] = decp[((size_t)t * BB + b) * AA + tid];
        vv[tid] = v_att[tid];
    }
    __syncthreads();
    const float4* dp4 = (const float4*)dp;
    const float4* vv4 = (const float4*)vv;
    for (int s = tid; s < SE; s += 256) {
        const float4* ep4 = (const float4*)(encp + ((size_t)s * BB + b) * AA);
        float a0 = 0.f;
        #pragma unroll 4
        for (int a = 0; a < AA / 4; a++) {
            float4 e = ep4[a], d = dp4[a], v = vv4[a];
            a0 += v.x * tanh_(e.x + d.x) + v.y * tanh_(e.y + d.y)
                + v.z * tanh_(e.z + d.z) + v.w * tanh_(e.w + d.w);
        }
        e_lds[s] = a0;
    }
    __syncthreads();
    float m = -1e30f;
    for (int s = tid; s < SE; s += 256) m = fmaxf(m, e_lds[s]);
    #pragma unroll
    for (int o = 32; o > 0; o >>= 1) m = fmaxf(m, __shfl_xor(m, o));
    if ((tid & 63) == 0) red[tid >> 6] = m;
    __syncthreads();
    m = fmaxf(fmaxf(red[0], red[1]), fmaxf(red[2], red[3]));
    float sum = 0.f;
    for (int s = tid; s < SE; s += 256) {
        float ex = __expf(e_lds[s] - m);
        e_lds[s] = ex;
        sum += ex;
    }
    #pragma unroll
    for (int o = 32; o > 0; o >>= 1) sum += __shfl_xor(sum, o);
    if ((tid & 63) == 0) red[4 + (tid >> 6)] = sum;
    __syncthreads();
    float inv = 1.f / (red[4] + red[5] + red[6] + red[7]);
    for (int s = tid; s < SE; s += 256)
        attn[((size_t)b * SD + t) * SE + s] = e_lds[s] * inv;
}

// ---------- context = attn^T @ output_enc, writes bf16 directly into x1 right half ----------
// grid: (32 b, 4 nchunk, 2 thalf)
__global__ __launch_bounds__(256) void k_context(const float* __restrict__ attn,   // [32][50][400]
                                                 const ushort* __restrict__ oe_bf, // [400][32][1024]
                                                 ushort* __restrict__ x1) {        // [1600][1536]
    int b = blockIdx.x, nc = blockIdx.y, th = blockIdx.z, tid = threadIdx.x;
    __shared__ float at[25][400];
    const float* ap = attn + ((size_t)b * SD + th * 25) * SE;
    for (int i = tid; i < 25 * 400; i += 256) at[i / 400][i % 400] = ap[i];
    __syncthreads();
    int n = nc * 256 + tid;
    float acc[25];
    #pragma unroll
    for (int i = 0; i < 25; i++) acc[i] = 0.f;
    for (int s = 0; s < SE; s += 4) {
        // 4 independent loads in flight (latency /4 at ~1 block/CU)
        float v0 = bf2f(oe_bf[((size_t)(s + 0) * BB + b) * 1024 + n]);
        float v1 = bf2f(oe_bf[((size_t)(s + 1) * BB + b) * 1024 + n]);
        float v2 = bf2f(oe_bf[((size_t)(s + 2) * BB + b) * 1024 + n]);
        float v3 = bf2f(oe_bf[((size_t)(s + 3) * BB + b) * 1024 + n]);
        #pragma unroll
        for (int tt = 0; tt < 25; tt++)
            acc[tt] += at[tt][s] * v0 + at[tt][s + 1] * v1
                     + at[tt][s + 2] * v2 + at[tt][s + 3] * v3;
    }
    #pragma unroll
    for (int tt = 0; tt < 25; tt++) {
        int row = (th * 25 + tt) * BB + b;
        x1[(size_t)row * 1536 + 512 + n] = f2bf(acc[tt]);
    }
}

// ---------- host ----------
extern "C" void kernel_launch(void* const* d_in, const int* in_sizes, int n_in,
                              void* d_out, int out_size, void* d_ws, size_t ws_size,
                              hipStream_t stream) {
    const float* output_enc = (const float*)d_in[0];
    const float* input_dec  = (const float*)d_in[1];
    const float* hidden_enc = (const float*)d_in[2];
    const float* cell_enc   = (const float*)d_in[3];
    const float* W_ih0 = (const float*)d_in[4],  *W_hh0 = (const float*)d_in[5];
    const float* b_ih0 = (const float*)d_in[6],  *b_hh0 = (const float*)d_in[7];
    const float* W_ih1 = (const float*)d_in[8],  *W_hh1 = (const float*)d_in[9];
    const float* b_ih1 = (const float*)d_in[10], *b_hh1 = (const float*)d_in[11];
    const float* W_red = (const float*)d_in[12], *b_red = (const float*)d_in[13];
    const float* W_att = (const float*)d_in[14], *b_att = (const float*)d_in[15];
    const float* v_att = (const float*)d_in[16];
    const float* W_v1  = (const float*)d_in[17], *b_v1 = (const float*)d_in[18];
    const float* W_v2  = (const float*)d_in[19], *b_v2 = (const float*)d_in[20];

    char* ws = (char*)d_ws;
    size_t off = 0;
    auto alloc = [&](size_t bytes) -> void* {
        void* p = ws + off;
        off += (bytes + 255) & ~(size_t)255;
        return p;
    };
    float*  h0m    = (float*)alloc(BB * HH * 4);
    float*  c0     = (float*)alloc(BB * HH * 4);
    float*  c1     = (float*)alloc(BB * HH * 4);
    ushort* AB     = (ushort*)alloc(2 * BB * 1024 * 2);               // [2][32][1024]
    float*  od     = (float*)alloc((size_t)SD * BB * HH * 4);         // 3.3 MB
    ushort* od_bf  = (ushort*)alloc((size_t)SD * BB * HH * 2);
    ushort* xd_bf  = (ushort*)alloc((size_t)SD * BB * INW * 2);       // 1.6 MB
    ushort* wih0b  = (ushort*)alloc((size_t)G4 * 512 * 2);            // 2 MB
    ushort* whh0b  = (ushort*)alloc((size_t)G4 * 512 * 2);            // 2 MB
    ushort* w1cat  = (ushort*)alloc((size_t)G4 * 1024 * 2);           // 4 MB
    float*  bsum0  = (float*)alloc(G4 * 4);
    float*  bsum1  = (float*)alloc(G4 * 4);
    float*  gx0    = (float*)alloc((size_t)SD * BB * G4 * 4);         // 13.1 MB
    ushort* oe_bf  = (ushort*)alloc((size_t)SE * BB * 1024 * 2);      // 26.2 MB
    ushort* wae    = (ushort*)alloc((size_t)AA * 1024 * 2);
    ushort* wad    = (ushort*)alloc((size_t)AA * 512 * 2);
    float*  encp   = (float*)alloc((size_t)SE * BB * AA * 4);         // 6.6 MB
    float*  decp   = (float*)alloc((size_t)SD * BB * AA * 4);
    float*  attn   = (float*)alloc((size_t)BB * SD * SE * 4);         // 2.6 MB
    ushort* x1     = (ushort*)alloc((size_t)1600 * 1536 * 2);         // 4.9 MB
    ushort* wv1    = (ushort*)alloc((size_t)VF * 1536 * 2);           // 3.1 MB
    ushort* y1     = (ushort*)alloc((size_t)1600 * VF * 2);           // 3.3 MB
    ushort* wv2    = (ushort*)alloc((size_t)VV * 1024 * 2);           // 65.5 MB

    // --- fused conversions: flat segs (blocks = elems/1024, all exact) ---
    {
        CvtFlatTab t;
        int nb = 0, k = 0;
        auto add = [&](const float* s, ushort* d, long n) {
            t.src[k] = s; t.dst[k] = d; nb += (int)(n / 1024); t.blk_end[k] = nb; k++;
        };
        add(input_dec, xd_bf, (long)SD * BB * INW);
        add(output_enc, oe_bf, (long)SE * BB * 1024);
        add(W_ih0, wih0b, (long)G4 * 512);
        add(W_hh0, whh0b, (long)G4 * 512);
        add(W_v1, wv1, (long)VF * 1536);
        add(W_v2, wv2, (long)VV * 1024);
        t.nseg = k;
        k_cvt_multi<<<nb, 256, 0, stream>>>(t);
    }
    {
        CvtStrTab t;
        int nb = 0, k = 0;
        auto add = [&](const float* s, ushort* d, int rows, int cols, int ss, int so, int ds, int dofs) {
            t.src[k] = s; t.dst[k] = d; t.ss[k] = ss; t.so[k] = so;
            t.ds[k] = ds; t.dofs[k] = dofs; t.c4n[k] = cols / 4;
            nb += rows * cols / 1024; t.blk_end[k] = nb; k++;
        };
        add(W_ih1, w1cat, G4, 512, 512, 0, 1024, 0);
        add(W_hh1, w1cat, G4, 512, 512, 0, 1024, 512);
        add(W_att, wae, AA, 1024, 1536, 0, 1024, 0);
        add(W_att, wad, AA, 512, 1536, 1024, 512, 0);
        t.nseg = k;
        k_cvt_str_multi<<<nb, 256, 0, stream>>>(t);
    }
    k_bsum<<<8, 256, 0, stream>>>(b_ih0, b_hh0, b_ih1, b_hh1, bsum0, bsum1);

    // --- fold encoder state through reduce_dim (also seeds bf16 AB halves) ---
    k_fold<<<dim3(2, 32, 4), 256, 0, stream>>>(hidden_enc, cell_enc, W_red, b_red,
                                               h0m, c0, c1, AB);

    // --- precompute layer-0 x-path gates for all timesteps ---
    k_gemm128<0><<<13 * 16, 256, 0, stream>>>(xd_bf, wih0b, gx0, nullptr, bsum0,
                                              SD * BB, G4, 512, 13);

    // --- pipelined LSTM: launch i = layer0[i] || layer1[i-1] ---
    for (int i = 0; i <= SD; i++) {
        const ushort* Aprev = AB + (size_t)((i + 1) & 1) * BB * 1024;
        ushort* ABdst = AB + (size_t)(i & 1) * BB * 1024;
        int t1c = (i > 0) ? (i - 1) : 0;
        k_cell<<<dim3(32, 2), 256, 0, stream>>>(Aprev, whh0b, w1cat,
                                                gx0 + (size_t)i * BB * G4, bsum1,
                                                c0, c1, h0m,
                                                od + (size_t)t1c * BB * HH,
                                                od_bf + (size_t)t1c * BB * HH,
                                                x1 + (size_t)t1c * BB * 1536,
                                                ABdst, (int)(i < SD), (int)(i > 0));
    }
    k_states<<<64, 256, 0, stream>>>(h0m, od + (size_t)(SD - 1) * BB * HH, c0, c1,
                                     (float*)d_out + (size_t)SD * BB * VV);

    // --- attention ---
    k_gemm128<0><<<100, 256, 0, stream>>>(oe_bf, wae, encp, nullptr,
                                          (const float*)nullptr, SE * BB, AA, 1024, 100);
    k_gemm128<0><<<13, 256, 0, stream>>>(od_bf, wad, decp, nullptr,
                                         b_att, SD * BB, AA, 512, 13);
    k_scores<<<dim3(SD, BB), 256, 0, stream>>>(encp, decp, v_att, attn);
    k_context<<<dim3(32, 4, 2), 256, 0, stream>>>(attn, oe_bf, x1);

    // --- vocab MLP ---
    k_gemm128<1><<<13 * 8, 256, 0, stream>>>(x1, wv1, nullptr, y1, b_v1,
                                             1600, VF, 1536, 13);
    k_gemm128<0><<<13 * 250, 256, 0, stream>>>(y1, wv2, (float*)d_out, nullptr, b_v2,
                                               1600, VV, 1024, 13);
    (void)in_sizes; (void)n_in; (void)out_size; (void)ws_size;
}